// Round 16
// baseline (625.346 us; speedup 1.0000x reference)
//
#include <hip/hip_runtime.h>
#include <stddef.h>

#define NT 512       // timesteps
#define NI 28        // input dim
#define NH 64        // hidden dim
#define BT 8         // batch rows per block (2x dup into 16 MFMA rows)
#define CH 16        // x timesteps per staged chunk
#define XPh 36       // halfs per (t,b) x row: 28 payload + pad(28..35); pad[28]=1.0 (bias col)
#define HPh 72       // halfs per h row: 64 payload + 8 pad -> 144B
#define NTH 1024     // 16 waves: 0-7 layer0, 8-15 layer1; 2 gate-tiles per wave
#define XLD (CH*BT*7) // float4 loads per x chunk = 896
#define GPL (8*64*6) // gate plane: [b][u][6dw] floats per layer (stride 6 breaks bank alias)

typedef _Float16 f16x8 __attribute__((ext_vector_type(8)));
typedef float    f32x4 __attribute__((ext_vector_type(4)));

// 7-transcendental LSTM cell EW (kept from R12):
//   c' = [c*dBC + (C-1)*dA] / (dA*dBC),  h = (E-1)/((1+D)(E+1))
__device__ __forceinline__ float cell_ew(float gi, float gf, float gg, float go, float& cc) {
    float A = __expf(-gf), B = __expf(-gi), C = __expf(2.f * gg), D = __expf(-go);
    float dA  = 1.f + A;
    float dBC = (1.f + B) * (C + 1.f);
    float r   = __builtin_amdgcn_rcpf(dA * dBC);
    cc = r * (cc * dBC + (C - 1.f) * dA);
    float E = __expf(fminf(2.f * cc, 80.f));
    return (E - 1.f) * __builtin_amdgcn_rcpf((1.f + D) * (E + 1.f));
}

// LDS-only barrier (cross-wave communication in loop is via LDS only)
__device__ __forceinline__ void bar_lds() {
    asm volatile("s_waitcnt lgkmcnt(0)\n\ts_barrier" ::: "memory");
}

// flat x-chunk index [0,XLD) -> global float4 index
__device__ __forceinline__ size_t gxi(int idx, int n0, int b0) {
    int b   = idx / (CH * 7);
    int rem = idx - b * (CH * 7);
    int t   = rem / 7;
    int w7  = rem - t * 7;
    return ((size_t)(b0 + b) * NT + (n0 + t)) * 7 + w7;
}
__device__ __forceinline__ void xstoreh(_Float16* dst, int idx, float4 v) {
    int b   = idx / (CH * 7);
    int rem = idx - b * (CH * 7);
    int t   = rem / 7;
    int w7  = rem - t * 7;
    _Float16* row = dst + (t * BT + b) * XPh;
    _Float16 tmp[4] = { (_Float16)v.x, (_Float16)v.y, (_Float16)v.z, (_Float16)v.w };
    *(uint2*)(row + 4 * w7) = *(const uint2*)tmp;
}

__global__ __launch_bounds__(NTH, 4)
void lstm2_mfma(const float* __restrict__ x,
                const float* __restrict__ Wih0, const float* __restrict__ Whh0,
                const float* __restrict__ bih0, const float* __restrict__ bhh0,
                const float* __restrict__ Wih1, const float* __restrict__ Whh1,
                const float* __restrict__ bih1, const float* __restrict__ bhh1,
                const float* __restrict__ Wout, const float* __restrict__ bout,
                float* __restrict__ out, float* __restrict__ rlast)
{
    __shared__ __align__(16) _Float16 s_x[2][CH * BT * XPh];  // double-buffered x (f16)
    __shared__ __align__(16) _Float16 s_h0[2][BT * HPh];      // h0 parity buffers
    __shared__ __align__(16) _Float16 s_h1[2][BT * HPh];      // h1 parity buffers
    __shared__ __align__(16) float    s_g[2][GPL];            // gate exchange planes (l0, l1)
    __shared__ __align__(16) float    s_hf[BT * NH];          // fp32 h1(T-1) for head

    const int tid = threadIdx.x;
    const int ln  = tid & 63;
    const int wv  = tid >> 6;
    const int lay = wv >> 3;          // 0: waves 0-7 (layer0), 1: waves 8-15 (layer1)
    const int w8  = wv & 7;
    const int gp  = w8 >> 2;          // gate-pair of this wave: gates {2gp, 2gp+1}
    const int ublk= w8 & 3;           // 16-unit block
    const int b0  = blockIdx.x * BT;

    const int uc  = ln & 15;          // B/D column within tile
    const int q   = ln >> 4;          // lane quadrant
    const int kq  = q * 8;            // k offset of this lane's 8 A/B elements
    const int bA  = ln & 7;           // A batch row (rows 8-15 duplicate 0-7)
    const int u   = ublk * 16 + uc;   // unit of this lane's tile column
    const int bc  = w8;               // EW-assigned cell: batch=bc, unit=ln

    // ---------------- prologue: zero LDS, bias column, stage x chunk 0 ----------------
    #pragma unroll 1
    for (int i = tid; i < (int)(sizeof(s_x) / 4); i += NTH) ((int*)s_x)[i] = 0;
    #pragma unroll 1
    for (int i = tid; i < (int)((sizeof(s_h0) + sizeof(s_h1)) / 4); i += NTH) ((int*)s_h0)[i] = 0;
    __syncthreads();                       // zeroing visible before pad-col writes
    if (tid < 2 * CH * BT) {               // set x pad column k=28 to 1.0 (bias input)
        int buf = tid >> 7, r = tid & 127;
        s_x[buf][r * XPh + 28] = (_Float16)1.0f;
    }
    const float4* xg4 = (const float4*)x;
    if (tid < XLD) {
        float4 v = xg4[gxi(tid, 0, b0)];
        xstoreh(s_x[0], tid, v);
    }
    __syncthreads();

    const f32x4 z4 = { 0.f, 0.f, 0.f, 0.f };

    if (lay == 0) {
        // ---- layer0 wave: 2 gate-tiles {g=2gp+tt, units ublk}; phase A=MFMA, B=EW ----
        f16x8 B0[2], B1[2], B2[2];
        #pragma unroll
        for (int tt = 0; tt < 2; ++tt) {
            const int g = (2 * gp + tt) * 64 + u;
            const float bias0 = bih0[g] + bhh0[g];
            #pragma unroll
            for (int j = 0; j < 8; ++j) {
                int k = kq + j;
                float w0 = (k < NI) ? Wih0[g * NI + k] : (k == 28 ? bias0 : 0.f);
                B0[tt][j] = (_Float16)w0;
                B1[tt][j] = (_Float16)Whh0[g * NH + k];
                B2[tt][j] = (_Float16)Whh0[g * NH + 32 + k];
            }
        }
        float4 pfA; float cc = 0.f;
        #pragma unroll 1
        for (int n = 0; n <= NT + 1; ++n) {
            if ((n & 15) == 0 && n + CH < NT && tid < XLD)
                pfA = xg4[gxi(tid, n + CH, b0)];
            // -------- phase A: MFMA gates0(n), publish to gate plane --------
            if (n < NT) {
                const _Float16* xrow = s_x[(n >> 4) & 1] + ((n & 15) * BT + bA) * XPh;
                f16x8 Ax = *(const f16x8*)(xrow + kq);
                const _Float16* h0r = s_h0[(n - 1) & 1] + bA * HPh;
                f16x8 A0 = *(const f16x8*)(h0r + kq);
                f16x8 A1 = *(const f16x8*)(h0r + 32 + kq);
                f32x4 acc[2];
                #pragma unroll
                for (int tt = 0; tt < 2; ++tt) {
                    f32x4 a = __builtin_amdgcn_mfma_f32_16x16x32_f16(Ax, B0[tt], z4, 0, 0, 0);
                    a       = __builtin_amdgcn_mfma_f32_16x16x32_f16(A0, B1[tt], a, 0, 0, 0);
                    acc[tt] = __builtin_amdgcn_mfma_f32_16x16x32_f16(A1, B2[tt], a, 0, 0, 0);
                }
                if (q < 2) {               // rows 8-15 duplicate 0-7: lanes 0-31 publish
                    #pragma unroll
                    for (int i = 0; i < 4; ++i) {
                        int b   = q * 4 + i;
                        int idx = ((b << 6) + u) * 6 + (gp << 1);
                        *(float2*)&s_g[0][idx] = make_float2(acc[0][i], acc[1][i]);
                    }
                }
            }
            bar_lds();
            // -------- phase B: EW of own cell (batch bc, unit ln) --------
            if (n < NT) {
                int ridx = ((bc << 6) + ln) * 6;
                float2 p01 = *(const float2*)&s_g[0][ridx];
                float2 p23 = *(const float2*)&s_g[0][ridx + 2];
                float h = cell_ew(p01.x, p01.y, p23.x, p23.y, cc);
                s_h0[n & 1][bc * HPh + ln] = (_Float16)h;
            }
            if ((n & 15) == 15 && n + 1 < NT && tid < XLD)
                xstoreh(s_x[((n >> 4) + 1) & 1], tid, pfA);
            bar_lds();
        }
    } else {
        // ---- layer1 wave: staggered — phase A=EW(gates1(n-2)), phase B=MFMA(gates1(n-1)) ----
        f16x8 B0[2], B1[2], B2[2], B3[2]; f32x4 bseed[2];
        #pragma unroll
        for (int tt = 0; tt < 2; ++tt) {
            const int g = (2 * gp + tt) * 64 + u;
            const float bf = bih1[g] + bhh1[g];
            bseed[tt] = (f32x4){ bf, bf, bf, bf };
            #pragma unroll
            for (int j = 0; j < 8; ++j) {
                int k = kq + j;
                B0[tt][j] = (_Float16)Wih1[g * NH + k];
                B1[tt][j] = (_Float16)Wih1[g * NH + 32 + k];
                B2[tt][j] = (_Float16)Whh1[g * NH + k];
                B3[tt][j] = (_Float16)Whh1[g * NH + 32 + k];
            }
        }
        float4 pfA; float cc = 0.f;
        #pragma unroll 1
        for (int n = 0; n <= NT + 1; ++n) {
            if ((n & 15) == 0 && n + CH < NT && tid < XLD)
                pfA = xg4[gxi(tid, n + CH, b0)];
            // -------- phase A: EW gates1(n-2) -> h1(n-2) --------
            if (n >= 2) {
                int ridx = ((bc << 6) + ln) * 6;
                float2 p01 = *(const float2*)&s_g[1][ridx];
                float2 p23 = *(const float2*)&s_g[1][ridx + 2];
                float h = cell_ew(p01.x, p01.y, p23.x, p23.y, cc);
                if (n <= NT) {
                    s_h1[n & 1][bc * HPh + ln] = (_Float16)h;   // slot (n-2)&1 == n&1
                } else {                    // n == NT+1: h1(NT-1) -> outputs
                    rlast[(size_t)(b0 + bc) * NH + ln] = h;
                    s_hf[bc * NH + ln] = h;
                }
            }
            bar_lds();
            // -------- phase B: MFMA gates1(n-1), publish --------
            if (n >= 1 && n <= NT) {
                const _Float16* h0r = s_h0[(n - 1) & 1] + bA * HPh;  // h0(n-1)
                const _Float16* h1r = s_h1[n & 1] + bA * HPh;        // h1(n-2)
                f16x8 A0 = *(const f16x8*)(h0r + kq);
                f16x8 A1 = *(const f16x8*)(h0r + 32 + kq);
                f16x8 A2 = *(const f16x8*)(h1r + kq);
                f16x8 A3 = *(const f16x8*)(h1r + 32 + kq);
                f32x4 acc[2];
                #pragma unroll
                for (int tt = 0; tt < 2; ++tt) {   // depth-4, bias-seeded
                    f32x4 a = __builtin_amdgcn_mfma_f32_16x16x32_f16(A0, B0[tt], bseed[tt], 0, 0, 0);
                    a       = __builtin_amdgcn_mfma_f32_16x16x32_f16(A1, B1[tt], a, 0, 0, 0);
                    a       = __builtin_amdgcn_mfma_f32_16x16x32_f16(A2, B2[tt], a, 0, 0, 0);
                    acc[tt] = __builtin_amdgcn_mfma_f32_16x16x32_f16(A3, B3[tt], a, 0, 0, 0);
                }
                if (q < 2) {
                    #pragma unroll
                    for (int i = 0; i < 4; ++i) {
                        int b   = q * 4 + i;
                        int idx = ((b << 6) + u) * 6 + (gp << 1);
                        *(float2*)&s_g[1][idx] = make_float2(acc[0][i], acc[1][i]);
                    }
                }
            }
            if ((n & 15) == 15 && n + 1 < NT && tid < XLD)
                xstoreh(s_x[((n >> 4) + 1) & 1], tid, pfA);
            bar_lds();
        }
    }

    __syncthreads();   // l1's s_hf visible to head lanes

    // ---------------- head: out = r_last @ Wout.T + bout ----------------
    if (tid < BT * 10) {
        int b = tid / 10, o = tid - 10 * (tid / 10);
        float a = bout[o];
        #pragma unroll
        for (int uu = 0; uu < NH; ++uu) a += Wout[o * NH + uu] * s_hf[b * NH + uu];
        out[(size_t)(b0 + b) * 10 + o] = a;
    }
}

extern "C" void kernel_launch(void* const* d_in, const int* in_sizes, int n_in,
                              void* d_out, int out_size, void* d_ws, size_t ws_size,
                              hipStream_t stream) {
    const float* x    = (const float*)d_in[0];
    const float* Wih0 = (const float*)d_in[1];
    const float* Whh0 = (const float*)d_in[2];
    const float* bih0 = (const float*)d_in[3];
    const float* bhh0 = (const float*)d_in[4];
    const float* Wih1 = (const float*)d_in[5];
    const float* Whh1 = (const float*)d_in[6];
    const float* bih1 = (const float*)d_in[7];
    const float* bhh1 = (const float*)d_in[8];
    const float* Wout = (const float*)d_in[9];
    const float* bout = (const float*)d_in[10];

    const int B = in_sizes[0] / (NT * NI);      // 2048
    float* out   = (float*)d_out;               // [B,10]
    float* rlast = out + (size_t)B * 10;        // [B,64]

    dim3 grid(B / BT), block(NTH);              // 256 blocks -> 1 block/CU, 16 waves
    hipLaunchKernelGGL(lstm2_mfma, grid, block, 0, stream,
                       x, Wih0, Whh0, bih0, bhh0, Wih1, Whh1, bih1, bhh1,
                       Wout, bout, out, rlast);
}

// Round 18
// 454.503 us; speedup vs baseline: 1.3759x; 1.3759x over previous
//
#include <hip/hip_runtime.h>
#include <stddef.h>

#define NT 512       // timesteps
#define NI 28        // input dim
#define NH 64        // hidden dim
#define BT 8         // batch rows per block (2x dup into 16 MFMA rows)
#define CH 16        // x timesteps per staged chunk
#define XPh 36       // halfs per (t,b) x row: 28 payload + pad(28..35); pad[28]=1.0 (bias col)
#define HPh 72       // halfs per h row: 64 payload + 8 pad -> 144B (36-dw bank stride)
#define NTH 512      // 8 waves: 0-3 layer0, 4-7 layer1

typedef _Float16 f16x8 __attribute__((ext_vector_type(8)));
typedef float    f32x4 __attribute__((ext_vector_type(4)));

#define LOG2E  1.4426950408889634f   // i/f/o gate pre-scale (exp -> exp2)
#define LOG2E2 2.8853900817779268f   // g gate pre-scale (e^{2g} -> 2^{g'})

// 7-transcendental LSTM cell EW; gates arrive PRE-SCALED by log2e (i,f,o) and
// 2*log2e (g) via the weight fragments, so every exp is a bare v_exp_f32:
//   A=2^-gf', B=2^-gi', C=2^gg' (== e^{2gg}), D=2^-go', E=2^{2*log2e*cc}
//   c' = [c*dBC + (C-1)*dA] / (dA*dBC),  h = (E-1)/((1+D)(E+1))
// (E-arg clamped at 115 ~ e^80: h saturates to sigm(go), same as before.)
__device__ __forceinline__ float cell_ew(float gi, float gf, float gg, float go, float& cc) {
    float A = __builtin_amdgcn_exp2f(-gf);
    float B = __builtin_amdgcn_exp2f(-gi);
    float C = __builtin_amdgcn_exp2f(gg);
    float D = __builtin_amdgcn_exp2f(-go);
    float dA  = 1.f + A;
    float dBC = (1.f + B) * (C + 1.f);
    float r   = __builtin_amdgcn_rcpf(dA * dBC);
    cc = r * (cc * dBC + (C - 1.f) * dA);
    float E = __builtin_amdgcn_exp2f(fminf(LOG2E2 * cc, 115.f));
    return (E - 1.f) * __builtin_amdgcn_rcpf((1.f + D) * (E + 1.f));
}

// LDS-only barrier: cross-wave communication in the main loops is exclusively
// through LDS, so lgkmcnt(0)+s_barrier suffices; in-flight global prefetch
// (VGPR dest) stays in flight across barriers, guarded by compiler vmcnt at use.
__device__ __forceinline__ void bar_lds() {
    asm volatile("s_waitcnt lgkmcnt(0)\n\ts_barrier" ::: "memory");
}

// flat x-chunk index [0,896) -> global float4 index
__device__ __forceinline__ size_t gxi(int idx, int n0, int b0) {
    int b   = idx / (CH * 7);
    int rem = idx - b * (CH * 7);
    int t   = rem / 7;
    int w7  = rem - t * 7;
    return ((size_t)(b0 + b) * NT + (n0 + t)) * 7 + w7;
}
// convert float4 -> f16x4, store into x chunk buffer
__device__ __forceinline__ void xstoreh(_Float16* dst, int idx, float4 v) {
    int b   = idx / (CH * 7);
    int rem = idx - b * (CH * 7);
    int t   = rem / 7;
    int w7  = rem - t * 7;
    _Float16* row = dst + (t * BT + b) * XPh;
    _Float16 tmp[4] = { (_Float16)v.x, (_Float16)v.y, (_Float16)v.z, (_Float16)v.w };
    *(uint2*)(row + 4 * w7) = *(const uint2*)tmp;
}

__global__ __launch_bounds__(NTH, 2)
void lstm2_mfma(const float* __restrict__ x,
                const float* __restrict__ Wih0, const float* __restrict__ Whh0,
                const float* __restrict__ bih0, const float* __restrict__ bhh0,
                const float* __restrict__ Wih1, const float* __restrict__ Whh1,
                const float* __restrict__ bih1, const float* __restrict__ bhh1,
                const float* __restrict__ Wout, const float* __restrict__ bout,
                float* __restrict__ out, float* __restrict__ rlast)
{
    __shared__ __align__(16) _Float16 s_x[2][CH * BT * XPh];  // double-buffered x (f16)
    __shared__ __align__(16) _Float16 s_h0[2][BT * HPh];      // h0 parity buffers
    __shared__ __align__(16) _Float16 s_h1[2][BT * HPh];      // h1 parity buffers
    __shared__ __align__(16) float    s_hf[BT * NH];          // fp32 h1(T-1) for head

    const int tid = threadIdx.x;
    const int ln  = tid & 63;
    const int wv  = tid >> 6;
    const int lay = wv >> 2;          // 0: layer0 waves, 1: layer1 waves
    const int w4  = wv & 3;           // 16-unit slice within the layer
    const int b0  = blockIdx.x * BT;

    const int colB = ln & 15;         // B/D column within tile
    const int kq   = (ln >> 4) * 8;   // k offset of this lane's 8 A/B elements
    const int bA   = ln & 7;          // A batch row (rows 8-15 duplicate 0-7)
    const int ue   = w4 * 16 + colB;  // hidden unit of this lane's tile column
    const int m0   = (ln >> 4) * 4;   // first D row of this lane's fragment
    const int rq   = (ln >= 32) ? 2 : 0;        // acc pair handled by this lane
    const int bm0  = (m0 + rq) & 7;             // batch of cell 0
    const int bm1  = (m0 + rq + 1) & 7;         // batch of cell 1
    const bool hi  = (rq != 0);
    const int off0 = bm0 * HPh + ue;            // h write offsets
    const int off1 = bm1 * HPh + ue;

    // ---------------- prologue: zero LDS, bias column, stage x chunk 0 ----------------
    #pragma unroll 1
    for (int i = tid; i < (int)(sizeof(s_x) / 4); i += NTH) ((int*)s_x)[i] = 0;
    #pragma unroll 1
    for (int i = tid; i < (int)((sizeof(s_h0) + sizeof(s_h1)) / 4); i += NTH) ((int*)s_h0)[i] = 0;
    __syncthreads();                       // zeroing visible before pad-col writes
    if (tid < 2 * CH * BT) {               // set x pad column k=28 to 1.0 (bias input)
        int buf = tid >> 7, r = tid & 127;
        s_x[buf][r * XPh + 28] = (_Float16)1.0f;
    }

    const float4* xg4 = (const float4*)x;
    {
        float4 v = xg4[gxi(tid, 0, b0)];
        xstoreh(s_x[0], tid, v);
        if (tid < 384) {
            float4 v2 = xg4[gxi(tid + NTH, 0, b0)];
            xstoreh(s_x[0], tid + NTH, v2);
        }
    }
    __syncthreads();

    const f32x4 z4 = { 0.f, 0.f, 0.f, 0.f };
    float cc0 = 0.f, cc1 = 0.f;        // this lane's 2 cell states
    float4 pfA, pfB;                   // x prefetch registers

    if (lay == 0) {
        // ---- B fragments, layer0 (f16), pre-scaled for exp2 EW ----
        f16x8 B0[4], B1[4], B2[4];
        #pragma unroll
        for (int t = 0; t < 4; ++t) {
            const int g = 64 * t + ue;
            const float sc = (t == 2) ? LOG2E2 : LOG2E;   // gate order i,f,g,o
            const float bias0 = (bih0[g] + bhh0[g]) * sc;
            #pragma unroll
            for (int j = 0; j < 8; ++j) {
                int k = kq + j;
                float w0 = (k < NI) ? Wih0[g * NI + k] * sc : (k == 28 ? bias0 : 0.f);
                B0[t][j] = (_Float16)w0;
                B1[t][j] = (_Float16)(Whh0[g * NH + k] * sc);
                B2[t][j] = (_Float16)(Whh0[g * NH + 32 + k] * sc);
            }
        }
        f32x4 accx[4];   // x-part of gates, computed one step ahead (barrier shadow)
        #pragma unroll 1
        for (int n = 0; n <= NT; ++n) {
            if ((n & 15) == 0 && n + CH < NT) {
                pfA = xg4[gxi(tid, n + CH, b0)];
                if (tid < 384) pfB = xg4[gxi(tid + NTH, n + CH, b0)];
            }
            if (n < NT) {
                if ((n & 15) == 0) {   // chunk-start: x-part not hoisted, compute in-step
                    const _Float16* xrow = s_x[(n >> 4) & 1] + ((n & 15) * BT + bA) * XPh;
                    f16x8 Ax = *(const f16x8*)(xrow + kq);
                    #pragma unroll
                    for (int t = 0; t < 4; ++t)
                        accx[t] = __builtin_amdgcn_mfma_f32_16x16x32_f16(Ax, B0[t], z4, 0, 0, 0);
                }
                const _Float16* h0r = s_h0[(n - 1) & 1] + bA * HPh;
                f16x8 A0 = *(const f16x8*)(h0r + kq);
                f16x8 A1 = *(const f16x8*)(h0r + 32 + kq);
                f32x4 acc[4];
                __builtin_amdgcn_s_setprio(1);
                #pragma unroll
                for (int t = 0; t < 4; ++t) {   // post-barrier chain: depth 2
                    f32x4 a = __builtin_amdgcn_mfma_f32_16x16x32_f16(A0, B1[t], accx[t], 0, 0, 0);
                    acc[t]  = __builtin_amdgcn_mfma_f32_16x16x32_f16(A1, B2[t], a, 0, 0, 0);
                }
                __builtin_amdgcn_s_setprio(0);
                // all-lane EW (bias already in via x pad column); exp2 7-trans cell
                float g00 = hi ? acc[0][2] : acc[0][0];
                float g10 = hi ? acc[1][2] : acc[1][0];
                float g20 = hi ? acc[2][2] : acc[2][0];
                float g30 = hi ? acc[3][2] : acc[3][0];
                float g01 = hi ? acc[0][3] : acc[0][1];
                float g11 = hi ? acc[1][3] : acc[1][1];
                float g21 = hi ? acc[2][3] : acc[2][1];
                float g31 = hi ? acc[3][3] : acc[3][1];
                _Float16* hw = s_h0[n & 1];
                hw[off0] = (_Float16)cell_ew(g00, g10, g20, g30, cc0);
                hw[off1] = (_Float16)cell_ew(g01, g11, g21, g31, cc1);
                // hoist next step's x-part into the barrier shadow (x is stable
                // within a chunk; skip at chunk boundary where buffer is rewritten)
                if ((n & 15) != 15 && n + 1 < NT) {
                    const _Float16* xrow2 = s_x[((n + 1) >> 4) & 1] + (((n + 1) & 15) * BT + bA) * XPh;
                    f16x8 Ax2 = *(const f16x8*)(xrow2 + kq);
                    #pragma unroll
                    for (int t = 0; t < 4; ++t)
                        accx[t] = __builtin_amdgcn_mfma_f32_16x16x32_f16(Ax2, B0[t], z4, 0, 0, 0);
                }
            }
            if ((n & 15) == 15 && n + 1 < NT) {
                _Float16* dst = s_x[((n >> 4) + 1) & 1];
                xstoreh(dst, tid, pfA);
                if (tid < 384) xstoreh(dst, tid + NTH, pfB);
            }
            bar_lds();
        }
    } else {
        // ---- B fragments, layer1 (f16), pre-scaled for exp2 EW ----
        f16x8 B0[4], B1[4], B2[4], B3[4]; f32x4 bseed[4];
        #pragma unroll
        for (int t = 0; t < 4; ++t) {
            const int g = 64 * t + ue;
            const float sc = (t == 2) ? LOG2E2 : LOG2E;
            const float bf = (bih1[g] + bhh1[g]) * sc;
            bseed[t] = (f32x4){ bf, bf, bf, bf };   // bias seeded as MFMA C-operand
            #pragma unroll
            for (int j = 0; j < 8; ++j) {
                int k = kq + j;
                B0[t][j] = (_Float16)(Wih1[g * NH + k] * sc);
                B1[t][j] = (_Float16)(Wih1[g * NH + 32 + k] * sc);
                B2[t][j] = (_Float16)(Whh1[g * NH + k] * sc);
                B3[t][j] = (_Float16)(Whh1[g * NH + 32 + k] * sc);
            }
        }
        #pragma unroll 1
        for (int n = 0; n <= NT; ++n) {
            if ((n & 15) == 0 && n + CH < NT) {
                pfA = xg4[gxi(tid, n + CH, b0)];
                if (tid < 384) pfB = xg4[gxi(tid + NTH, n + CH, b0)];
            }
            if (n >= 1) {
                const _Float16* h0r = s_h0[(n - 1) & 1] + bA * HPh;   // h0(n-1)
                const _Float16* h1r = s_h1[n & 1] + bA * HPh;         // h1(n-2)
                f16x8 A0 = *(const f16x8*)(h0r + kq);
                f16x8 A1 = *(const f16x8*)(h0r + 32 + kq);
                f16x8 A2 = *(const f16x8*)(h1r + kq);
                f16x8 A3 = *(const f16x8*)(h1r + 32 + kq);
                f32x4 accp[4], accq[4];
                __builtin_amdgcn_s_setprio(1);
                #pragma unroll
                for (int t = 0; t < 4; ++t) {   // two independent depth-2 chains
                    f32x4 p = __builtin_amdgcn_mfma_f32_16x16x32_f16(A0, B0[t], bseed[t], 0, 0, 0);
                    accp[t] = __builtin_amdgcn_mfma_f32_16x16x32_f16(A1, B1[t], p, 0, 0, 0);
                    f32x4 q = __builtin_amdgcn_mfma_f32_16x16x32_f16(A2, B2[t], z4, 0, 0, 0);
                    accq[t] = __builtin_amdgcn_mfma_f32_16x16x32_f16(A3, B3[t], q, 0, 0, 0);
                }
                __builtin_amdgcn_s_setprio(0);
                float g00 = (hi ? accp[0][2] : accp[0][0]) + (hi ? accq[0][2] : accq[0][0]);
                float g10 = (hi ? accp[1][2] : accp[1][0]) + (hi ? accq[1][2] : accq[1][0]);
                float g20 = (hi ? accp[2][2] : accp[2][0]) + (hi ? accq[2][2] : accq[2][0]);
                float g30 = (hi ? accp[3][2] : accp[3][0]) + (hi ? accq[3][2] : accq[3][0]);
                float g01 = (hi ? accp[0][3] : accp[0][1]) + (hi ? accq[0][3] : accq[0][1]);
                float g11 = (hi ? accp[1][3] : accp[1][1]) + (hi ? accq[1][3] : accq[1][1]);
                float g21 = (hi ? accp[2][3] : accp[2][1]) + (hi ? accq[2][3] : accq[2][1]);
                float g31 = (hi ? accp[3][3] : accp[3][1]) + (hi ? accq[3][3] : accq[3][1]);
                _Float16* hw = s_h1[(n - 1) & 1];
                float h0v = cell_ew(g00, g10, g20, g30, cc0);
                hw[off0] = (_Float16)h0v;
                float h1v = cell_ew(g01, g11, g21, g31, cc1);
                hw[off1] = (_Float16)h1v;
                if (n == NT) {
                    rlast[(size_t)(b0 + bm0) * NH + ue] = h0v;
                    rlast[(size_t)(b0 + bm1) * NH + ue] = h1v;
                    s_hf[bm0 * NH + ue] = h0v;
                    s_hf[bm1 * NH + ue] = h1v;
                }
            }
            if ((n & 15) == 15 && n + 1 < NT) {
                _Float16* dst = s_x[((n >> 4) + 1) & 1];
                xstoreh(dst, tid, pfA);
                if (tid < 384) xstoreh(dst, tid + NTH, pfB);
            }
            bar_lds();
        }
    }

    // ---------------- head: out = r_last @ Wout.T + bout ----------------
    if (tid < BT * 10) {
        int b = tid / 10, o = tid - 10 * (tid / 10);
        float a = bout[o];
        #pragma unroll
        for (int u = 0; u < NH; ++u) a += Wout[o * NH + u] * s_hf[b * NH + u];
        out[(size_t)(b0 + b) * 10 + o] = a;
    }
}

extern "C" void kernel_launch(void* const* d_in, const int* in_sizes, int n_in,
                              void* d_out, int out_size, void* d_ws, size_t ws_size,
                              hipStream_t stream) {
    const float* x    = (const float*)d_in[0];
    const float* Wih0 = (const float*)d_in[1];
    const float* Whh0 = (const float*)d_in[2];
    const float* bih0 = (const float*)d_in[3];
    const float* bhh0 = (const float*)d_in[4];
    const float* Wih1 = (const float*)d_in[5];
    const float* Whh1 = (const float*)d_in[6];
    const float* bih1 = (const float*)d_in[7];
    const float* bhh1 = (const float*)d_in[8];
    const float* Wout = (const float*)d_in[9];
    const float* bout = (const float*)d_in[10];

    const int B = in_sizes[0] / (NT * NI);      // 2048
    float* out   = (float*)d_out;               // [B,10]
    float* rlast = out + (size_t)B * 10;        // [B,64]

    dim3 grid(B / BT), block(NTH);              // 256 blocks -> 1 block/CU
    hipLaunchKernelGGL(lstm2_mfma, grid, block, 0, stream,
                       x, Wih0, Whh0, bih0, bhh0, Wih1, Whh1, bih1, bhh1,
                       Wout, bout, out, rlast);
}